// Round 2
// baseline (158.469 us; speedup 1.0000x reference)
//
#include <hip/hip_runtime.h>
#include <stdint.h>
#include <math.h>

#define D_MODEL 1024
#define NUM_HEADS 16
#define D_K 64
#define SEQ 2048
#define BATCH 2
#define SIM_THRESH 0.7f

#define TS 64          // tile size (square), one wave per tile
#define BK 32          // K chunk per MFMA step group
#define NIT (D_MODEL / BK)   // 32

#define NROWS (BATCH * SEQ)                       // 4096
#define VP_BLOCKS ((NROWS / TS) * (D_MODEL / TS)) // 64*16 = 1024
#define SIM_ROWB (SEQ / TS)                       // 32
#define SIM_TRI (SIM_ROWB * (SIM_ROWB + 1) / 2)   // 528
#define SIM_BLOCKS (SIM_TRI * BATCH)              // 1056
#define GRID (VP_BLOCKS + SIM_BLOCKS)             // 2080  (2080 % 8 == 0 -> simple XCD swizzle valid)

typedef __attribute__((ext_vector_type(8))) short bf16x8;
typedef __attribute__((ext_vector_type(4))) float f32x4;

static __device__ __forceinline__ unsigned short f2bf(float f) {
    unsigned int u = __float_as_uint(f);
    unsigned int r = (u + 0x7FFF + ((u >> 16) & 1)) >> 16;   // RNE
    return (unsigned short)r;
}
static __device__ __forceinline__ float bf2f(unsigned short u) {
    return __uint_as_float(((unsigned int)u) << 16);
}

// ---------- L1: normalize x rows -> bf16 (+norms, zero cnt)  AND  cast Wv -> bf16 ----------
__global__ __launch_bounds__(256) void k_prep(const float* __restrict__ x,
                                              const float* __restrict__ Wv,
                                              unsigned short* __restrict__ xn,
                                              unsigned short* __restrict__ Wvb,
                                              float* __restrict__ norms,
                                              int* __restrict__ cnt) {
    int bid = blockIdx.x, tid = threadIdx.x;
    if (bid < NROWS) {
        const float4* xr = (const float4*)(x + (size_t)bid * D_MODEL);
        float4 vv = xr[tid];
        float ss = vv.x * vv.x + vv.y * vv.y + vv.z * vv.z + vv.w * vv.w;
        for (int off = 32; off > 0; off >>= 1) ss += __shfl_down(ss, off, 64);
        __shared__ float wsum[4];
        int lane = tid & 63, wv = tid >> 6;
        if (lane == 0) wsum[wv] = ss;
        __syncthreads();
        float nrm = sqrtf(wsum[0] + wsum[1] + wsum[2] + wsum[3]);
        float inv = 1.0f / fmaxf(nrm, 1e-12f);
        ushort4 o;
        o.x = f2bf(vv.x * inv); o.y = f2bf(vv.y * inv);
        o.z = f2bf(vv.z * inv); o.w = f2bf(vv.w * inv);
        *(ushort4*)(xn + (size_t)bid * D_MODEL + tid * 4) = o;
        if (tid == 0) { norms[bid] = nrm; cnt[bid] = 0; }
    } else {
        size_t i = (size_t)(bid - NROWS) * 256 + tid;   // float4 chunk index
        float4 w = ((const float4*)Wv)[i];
        ushort4 o;
        o.x = f2bf(w.x); o.y = f2bf(w.y); o.z = f2bf(w.z); o.w = f2bf(w.w);
        *(ushort4*)(Wvb + i * 4) = o;
    }
}

// ---------- L2: barrier-free fused V-proj (tiles 0..1023) + symmetric sim/count ----------
// One wave (64 threads) per 64x64 output tile. NO LDS, NO __syncthreads: MFMA fragments
// are loaded straight from global. One bf16x8 load per lane covers rows r..r+16 x cols
// kk..kk+32 = 16 fully-consumed 64B lines; working set (10 MB) is L2/L3-resident.
// 4x4 frags of 16x16x32 bf16 MFMA, 2-deep register pipeline, zero barriers.
__global__ __launch_bounds__(64) void k_main(const unsigned short* __restrict__ xn,
                                             const unsigned short* __restrict__ Wvb,
                                             const float* __restrict__ bv,
                                             const float* __restrict__ norms,
                                             int* __restrict__ cnt,
                                             float* __restrict__ out) {
    // XCD-aware bijective swizzle (2080 % 8 == 0): each XCD gets a contiguous 260-tile chunk
    int bid0 = blockIdx.x;
    int bid = (bid0 & 7) * (GRID / 8) + (bid0 >> 3);
    int lane = threadIdx.x;
    int lrow = lane & 15, quad = lane >> 4;

    const unsigned short* Asrc;
    const unsigned short* Bsrc;
    int rowBase, colBase;
    bool isV;
    int b = 0, bi = 0, bj = 0;
    if (bid < VP_BLOCKS) {
        isV = true;
        rowBase = (bid >> 4) * TS;      // 64 row-blocks
        colBase = (bid & 15) * TS;      // 16 col-blocks
        Asrc = xn + (size_t)rowBase * D_MODEL;
        Bsrc = Wvb + (size_t)colBase * D_MODEL;
    } else {
        isV = false;
        int sidx = bid - VP_BLOCKS;
        b = (sidx >= SIM_TRI) ? 1 : 0;
        int r = sidx - b * SIM_TRI;
        bi = 0;
        while (r >= SIM_ROWB - bi) { r -= SIM_ROWB - bi; ++bi; }
        bj = bi + r;
        rowBase = bi * TS;              // batch-local
        colBase = bj * TS;
        const unsigned short* base = xn + (size_t)b * SEQ * D_MODEL;
        Asrc = base + (size_t)rowBase * D_MODEL;
        Bsrc = base + (size_t)colBase * D_MODEL;
    }

    // per-lane fragment base pointers (fragment i covers tile rows i*16 + lrow)
    const unsigned short* ap[4];
    const unsigned short* bp[4];
#pragma unroll
    for (int i = 0; i < 4; ++i) {
        ap[i] = Asrc + (size_t)(i * 16 + lrow) * D_MODEL + quad * 8;
        bp[i] = Bsrc + (size_t)(i * 16 + lrow) * D_MODEL + quad * 8;
    }

    f32x4 acc[4][4] = {};
    bf16x8 a0[4], b0[4], a1[4], b1[4];

#pragma unroll
    for (int i = 0; i < 4; ++i) {
        a0[i] = *(const bf16x8*)(ap[i]);
        b0[i] = *(const bf16x8*)(bp[i]);
    }
    for (int it = 0; it < NIT; it += 2) {
        // prefetch it+1 (NIT even -> always valid)
#pragma unroll
        for (int i = 0; i < 4; ++i) {
            a1[i] = *(const bf16x8*)(ap[i] + (it + 1) * BK);
            b1[i] = *(const bf16x8*)(bp[i] + (it + 1) * BK);
        }
#pragma unroll
        for (int mt = 0; mt < 4; ++mt)
#pragma unroll
            for (int nt = 0; nt < 4; ++nt)
                acc[mt][nt] = __builtin_amdgcn_mfma_f32_16x16x32_bf16(a0[mt], b0[nt], acc[mt][nt], 0, 0, 0);
        if (it + 2 < NIT) {
#pragma unroll
            for (int i = 0; i < 4; ++i) {
                a0[i] = *(const bf16x8*)(ap[i] + (it + 2) * BK);
                b0[i] = *(const bf16x8*)(bp[i] + (it + 2) * BK);
            }
        }
#pragma unroll
        for (int mt = 0; mt < 4; ++mt)
#pragma unroll
            for (int nt = 0; nt < 4; ++nt)
                acc[mt][nt] = __builtin_amdgcn_mfma_f32_16x16x32_bf16(a1[mt], b1[nt], acc[mt][nt], 0, 0, 0);
    }

    if (isV) {
#pragma unroll
        for (int nt = 0; nt < 4; ++nt) {
            int n = colBase + nt * 16 + lrow;
            float bn = bv[n];
            int h = n >> 6, j = n & 63;
#pragma unroll
            for (int mt = 0; mt < 4; ++mt) {
#pragma unroll
                for (int r = 0; r < 4; ++r) {
                    int m = rowBase + mt * 16 + quad * 4 + r;
                    float val = acc[mt][nt][r] * norms[m] + bn;
                    int bb = m >> 11, s = m & (SEQ - 1);
                    out[(((size_t)(bb * NUM_HEADS + h)) * SEQ + s) * D_K + j] = val;
                }
            }
        }
    } else {
        int* cb = cnt + b * SEQ;
        bool diag = (bi == bj);
#pragma unroll
        for (int nt = 0; nt < 4; ++nt) {
            int n = colBase + nt * 16 + lrow;
#pragma unroll
            for (int mt = 0; mt < 4; ++mt) {
#pragma unroll
                for (int r = 0; r < 4; ++r) {
                    int m = rowBase + mt * 16 + quad * 4 + r;
                    if (acc[mt][nt][r] > SIM_THRESH) {
                        atomicAdd(&cb[m], 1);
                        if (!diag) atomicAdd(&cb[n], 1);
                    }
                }
            }
        }
    }
}

// ---------- L3: fix rows with cnt != 1 (cold; cnt==1 rows already hold out = v row) ----------
// V rows are recomputed on the fly here (k_main does not materialize v).
__global__ __launch_bounds__(256) void k_fix(
    const float* __restrict__ x,
    const float* __restrict__ Wq, const float* __restrict__ bq,
    const float* __restrict__ Wk, const float* __restrict__ bk,
    const float* __restrict__ Wv, const float* __restrict__ bv,
    const unsigned short* __restrict__ xn,
    const int* __restrict__ cnt,
    float* __restrict__ out)
{
    int tid = threadIdx.x;
    int rowBase = blockIdx.x * 256;

    __shared__ int list[256];
    __shared__ int nlist;
    if (tid == 0) nlist = 0;
    __syncthreads();
    int grow = rowBase + tid;
    if (cnt[grow] != 1) { int p = atomicAdd(&nlist, 1); list[p] = grow; }
    __syncthreads();
    int nfix = nlist;
    if (nfix == 0) return;

    __shared__ uint8_t mrow[SEQ];
    __shared__ float q_row[D_MODEL];
    __shared__ float k_row[D_MODEL];
    __shared__ float v_row[D_MODEL];
    __shared__ float accO[D_MODEL];
    __shared__ float m_h[NUM_HEADS], l_h[NUM_HEADS], alpha_h[NUM_HEADS], p_h[NUM_HEADS];

    for (int li = 0; li < nfix; ++li) {
        int row = list[li];
        int b = row >> 11, s = row & (SEQ - 1);

        const unsigned short* xs = xn + (size_t)row * D_MODEL;
        for (int t = tid; t < SEQ; t += 256) {
            const unsigned short* xt = xn + ((size_t)b * SEQ + t) * D_MODEL;
            float d = 0.f;
            for (int k = 0; k < D_MODEL; ++k) d += bf2f(xs[k]) * bf2f(xt[k]);
            mrow[t] = (d > SIM_THRESH) ? 1 : 0;
        }

        const float* xrow = x + (size_t)row * D_MODEL;
        for (int c = tid; c < D_MODEL; c += 256) {
            const float* w = Wq + (size_t)c * D_MODEL;
            float acc = bq[c];
            for (int d = 0; d < D_MODEL; ++d) acc += xrow[d] * w[d];
            q_row[c] = acc;
            accO[c] = 0.f;
        }
        if (tid < NUM_HEADS) { m_h[tid] = -INFINITY; l_h[tid] = 0.f; }
        __syncthreads();

        for (int t = 0; t < SEQ; ++t) {
            if (!mrow[t]) continue;
            const float* xt = x + ((size_t)b * SEQ + t) * D_MODEL;
            for (int c = tid; c < D_MODEL; c += 256) {
                const float* wk = Wk + (size_t)c * D_MODEL;
                const float* wv = Wv + (size_t)c * D_MODEL;
                float ak = bk[c], av = bv[c];
                for (int d = 0; d < D_MODEL; ++d) {
                    float xv = xt[d];
                    ak += xv * wk[d];
                    av += xv * wv[d];
                }
                k_row[c] = ak;
                v_row[c] = av;
            }
            __syncthreads();
            if (tid < NUM_HEADS) {
                float sc = 0.f;
                for (int j = 0; j < D_K; ++j) sc += q_row[tid * D_K + j] * k_row[tid * D_K + j];
                sc *= 0.125f;
                float mnew = fmaxf(m_h[tid], sc);
                float alpha = expf(m_h[tid] - mnew);
                float p = expf(sc - mnew);
                l_h[tid] = l_h[tid] * alpha + p;
                m_h[tid] = mnew;
                alpha_h[tid] = alpha;
                p_h[tid] = p;
            }
            __syncthreads();
            for (int c = tid; c < D_MODEL; c += 256) {
                int h = c >> 6;
                accO[c] = accO[c] * alpha_h[h] + p_h[h] * v_row[c];
            }
            __syncthreads();
        }
        for (int c = tid; c < D_MODEL; c += 256) {
            int h = c >> 6, j = c & 63;
            out[(((size_t)(b * NUM_HEADS + h)) * SEQ + s) * D_K + j] = accO[c] / l_h[h];
        }
        __syncthreads();
    }
}

extern "C" void kernel_launch(void* const* d_in, const int* in_sizes, int n_in,
                              void* d_out, int out_size, void* d_ws, size_t ws_size,
                              hipStream_t stream) {
    const float* x  = (const float*)d_in[0];
    const float* Wq = (const float*)d_in[1];
    const float* bq = (const float*)d_in[2];
    const float* Wk = (const float*)d_in[3];
    const float* bk = (const float*)d_in[4];
    const float* Wv = (const float*)d_in[5];
    const float* bv = (const float*)d_in[6];
    float* out = (float*)d_out;

    // workspace: xn bf16 (8MB) | Wvb bf16 (2MB) | norms (16KB) | cnt (16KB)
    unsigned short* xn  = (unsigned short*)d_ws;
    unsigned short* Wvb = xn + (size_t)NROWS * D_MODEL;
    float* norms = (float*)(Wvb + (size_t)D_MODEL * D_MODEL);
    int* cnt     = (int*)(norms + NROWS);

    // L1: 4096 row-normalize blocks + 1024 Wv-cast blocks
    k_prep<<<NROWS + D_MODEL * D_MODEL / 1024, 256, 0, stream>>>(x, Wv, xn, Wvb, norms, cnt);

    // L2: 1024 vproj tiles + 1056 sim tiles, one wave each, barrier-free
    k_main<<<GRID, 64, 0, stream>>>(xn, Wvb, bv, norms, cnt, out);

    // L3: fix non-singleton rows (cold)
    k_fix<<<NROWS / 256, 256, 0, stream>>>(x, Wq, bq, Wk, bk, Wv, bv, xn, cnt, out);
}

// Round 3
// 155.030 us; speedup vs baseline: 1.0222x; 1.0222x over previous
//
#include <hip/hip_runtime.h>
#include <stdint.h>
#include <math.h>

#define D_MODEL 1024
#define NUM_HEADS 16
#define D_K 64
#define SEQ 2048
#define BATCH 2
#define SIM_THRESH 0.7f

#define TS 64          // tile size (square), one block per tile
#define BK 32          // K chunk per MFMA step
#define KW 256         // K range per wave (D_MODEL / 4 waves)
#define NIT_W (KW / BK)      // 8 iters per wave

#define NROWS (BATCH * SEQ)                       // 4096
#define VP_BLOCKS ((NROWS / TS) * (D_MODEL / TS)) // 64*16 = 1024
#define SIM_ROWB (SEQ / TS)                       // 32
#define SIM_TRI (SIM_ROWB * (SIM_ROWB + 1) / 2)   // 528
#define SIM_BLOCKS (SIM_TRI * BATCH)              // 1056
#define GRID (VP_BLOCKS + SIM_BLOCKS)             // 2080  (2080 % 8 == 0 -> XCD swizzle bijective)

typedef __attribute__((ext_vector_type(8))) short bf16x8;
typedef __attribute__((ext_vector_type(4))) float f32x4;

static __device__ __forceinline__ unsigned short f2bf(float f) {
    unsigned int u = __float_as_uint(f);
    unsigned int r = (u + 0x7FFF + ((u >> 16) & 1)) >> 16;   // RNE
    return (unsigned short)r;
}
static __device__ __forceinline__ float bf2f(unsigned short u) {
    return __uint_as_float(((unsigned int)u) << 16);
}

// ---------- L1: normalize x rows -> bf16 (+norms, zero cnt)  AND  cast Wv -> bf16 ----------
__global__ __launch_bounds__(256) void k_prep(const float* __restrict__ x,
                                              const float* __restrict__ Wv,
                                              unsigned short* __restrict__ xn,
                                              unsigned short* __restrict__ Wvb,
                                              float* __restrict__ norms,
                                              int* __restrict__ cnt) {
    int bid = blockIdx.x, tid = threadIdx.x;
    if (bid < NROWS) {
        const float4* xr = (const float4*)(x + (size_t)bid * D_MODEL);
        float4 vv = xr[tid];
        float ss = vv.x * vv.x + vv.y * vv.y + vv.z * vv.z + vv.w * vv.w;
        for (int off = 32; off > 0; off >>= 1) ss += __shfl_down(ss, off, 64);
        __shared__ float wsum[4];
        int lane = tid & 63, wv = tid >> 6;
        if (lane == 0) wsum[wv] = ss;
        __syncthreads();
        float nrm = sqrtf(wsum[0] + wsum[1] + wsum[2] + wsum[3]);
        float inv = 1.0f / fmaxf(nrm, 1e-12f);
        ushort4 o;
        o.x = f2bf(vv.x * inv); o.y = f2bf(vv.y * inv);
        o.z = f2bf(vv.z * inv); o.w = f2bf(vv.w * inv);
        *(ushort4*)(xn + (size_t)bid * D_MODEL + tid * 4) = o;
        if (tid == 0) { norms[bid] = nrm; cnt[bid] = 0; }
    } else {
        size_t i = (size_t)(bid - NROWS) * 256 + tid;   // float4 chunk index
        float4 w = ((const float4*)Wv)[i];
        ushort4 o;
        o.x = f2bf(w.x); o.y = f2bf(w.y); o.z = f2bf(w.z); o.w = f2bf(w.w);
        *(ushort4*)(Wvb + i * 4) = o;
    }
}

// ---------- L2: fused V-proj (tiles 0..1023) + symmetric sim/count (1024..2079) ----------
// One 256-thread block per 64x64 tile; 4 waves SPLIT K (wave w: cols w*256..w*256+255).
// Main loop is barrier-free: fragments load straight from global (working set is L2/L3-
// resident), each wave runs 8 iters x (8 loads + 16 MFMA) independently. Partials are
// summed by a 4-barrier LDS tree (2 x 16KB f32x4 buffers, contiguous rows -> conflict-free),
// then all 4 waves split the epilogue by fragment-row.
__global__ __launch_bounds__(256) void k_main(const unsigned short* __restrict__ xn,
                                              const unsigned short* __restrict__ Wvb,
                                              const float* __restrict__ bv,
                                              const float* __restrict__ norms,
                                              int* __restrict__ cnt,
                                              float* __restrict__ out) {
    __shared__ f32x4 red[2][16][64];   // 2 x 16 KB reduce buffers
    // XCD-aware bijective swizzle: each XCD gets a contiguous 260-tile chunk
    int bid0 = blockIdx.x;
    int bid = (bid0 & 7) * (GRID / 8) + (bid0 >> 3);
    int tid = threadIdx.x;
    int lane = tid & 63, wave = tid >> 6;
    int lrow = lane & 15, quad = lane >> 4;

    const unsigned short* Asrc;
    const unsigned short* Bsrc;
    int rowBase, colBase;
    bool isV;
    int b = 0, bi = 0, bj = 0;
    if (bid < VP_BLOCKS) {
        isV = true;
        rowBase = (bid >> 4) * TS;      // 64 row-blocks
        colBase = (bid & 15) * TS;      // 16 col-blocks
        Asrc = xn + (size_t)rowBase * D_MODEL;
        Bsrc = Wvb + (size_t)colBase * D_MODEL;
    } else {
        isV = false;
        int sidx = bid - VP_BLOCKS;
        b = (sidx >= SIM_TRI) ? 1 : 0;
        int r = sidx - b * SIM_TRI;
        bi = 0;
        while (r >= SIM_ROWB - bi) { r -= SIM_ROWB - bi; ++bi; }
        bj = bi + r;
        rowBase = bi * TS;              // batch-local
        colBase = bj * TS;
        const unsigned short* base = xn + (size_t)b * SEQ * D_MODEL;
        Asrc = base + (size_t)rowBase * D_MODEL;
        Bsrc = base + (size_t)colBase * D_MODEL;
    }

    // per-lane fragment base pointers; wave w starts at K offset w*KW
    const unsigned short* ap[4];
    const unsigned short* bp[4];
#pragma unroll
    for (int i = 0; i < 4; ++i) {
        ap[i] = Asrc + (size_t)(i * 16 + lrow) * D_MODEL + wave * KW + quad * 8;
        bp[i] = Bsrc + (size_t)(i * 16 + lrow) * D_MODEL + wave * KW + quad * 8;
    }

    f32x4 acc[4][4] = {};
    bf16x8 a0[4], b0[4], a1[4], b1[4];

#pragma unroll
    for (int i = 0; i < 4; ++i) {
        a0[i] = *(const bf16x8*)(ap[i]);
        b0[i] = *(const bf16x8*)(bp[i]);
    }
    for (int it = 0; it < NIT_W; it += 2) {
        // prefetch it+1 (NIT_W even -> always valid)
#pragma unroll
        for (int i = 0; i < 4; ++i) {
            a1[i] = *(const bf16x8*)(ap[i] + (it + 1) * BK);
            b1[i] = *(const bf16x8*)(bp[i] + (it + 1) * BK);
        }
#pragma unroll
        for (int mt = 0; mt < 4; ++mt)
#pragma unroll
            for (int nt = 0; nt < 4; ++nt)
                acc[mt][nt] = __builtin_amdgcn_mfma_f32_16x16x32_bf16(a0[mt], b0[nt], acc[mt][nt], 0, 0, 0);
        if (it + 2 < NIT_W) {
#pragma unroll
            for (int i = 0; i < 4; ++i) {
                a0[i] = *(const bf16x8*)(ap[i] + (it + 2) * BK);
                b0[i] = *(const bf16x8*)(bp[i] + (it + 2) * BK);
            }
        }
#pragma unroll
        for (int mt = 0; mt < 4; ++mt)
#pragma unroll
            for (int nt = 0; nt < 4; ++nt)
                acc[mt][nt] = __builtin_amdgcn_mfma_f32_16x16x32_bf16(a1[mt], b1[nt], acc[mt][nt], 0, 0, 0);
    }

    // ---- cross-wave K-reduction tree (4 barriers) ----
    // layout: red[buf][e4][lane], e4 = mt*4+nt; wave writes 16 contiguous 1KB rows.
    if (wave == 2) {
#pragma unroll
        for (int e4 = 0; e4 < 16; ++e4) red[0][e4][lane] = acc[e4 >> 2][e4 & 3];
    }
    if (wave == 3) {
#pragma unroll
        for (int e4 = 0; e4 < 16; ++e4) red[1][e4][lane] = acc[e4 >> 2][e4 & 3];
    }
    __syncthreads();
    if (wave == 0) {
#pragma unroll
        for (int e4 = 0; e4 < 16; ++e4) acc[e4 >> 2][e4 & 3] += red[0][e4][lane];
    }
    if (wave == 1) {
#pragma unroll
        for (int e4 = 0; e4 < 16; ++e4) acc[e4 >> 2][e4 & 3] += red[1][e4][lane];
    }
    __syncthreads();
    if (wave == 1) {
#pragma unroll
        for (int e4 = 0; e4 < 16; ++e4) red[0][e4][lane] = acc[e4 >> 2][e4 & 3];
    }
    __syncthreads();
    if (wave == 0) {
#pragma unroll
        for (int e4 = 0; e4 < 16; ++e4) {
            acc[e4 >> 2][e4 & 3] += red[0][e4][lane];
            red[0][e4][lane] = acc[e4 >> 2][e4 & 3];   // publish final
        }
    }
    __syncthreads();

    // ---- epilogue: wave w owns fragment-row mt = w ----
    int mt = wave;
    f32x4 fin[4];
#pragma unroll
    for (int nt = 0; nt < 4; ++nt) fin[nt] = red[0][mt * 4 + nt][lane];

    if (isV) {
#pragma unroll
        for (int nt = 0; nt < 4; ++nt) {
            int n = colBase + nt * 16 + lrow;
            float bn = bv[n];
            int h = n >> 6, j = n & 63;
#pragma unroll
            for (int r = 0; r < 4; ++r) {
                int m = rowBase + mt * 16 + quad * 4 + r;
                float val = fin[nt][r] * norms[m] + bn;
                int bb = m >> 11, s = m & (SEQ - 1);
                out[(((size_t)(bb * NUM_HEADS + h)) * SEQ + s) * D_K + j] = val;
            }
        }
    } else {
        int* cb = cnt + b * SEQ;
        bool diag = (bi == bj);
#pragma unroll
        for (int nt = 0; nt < 4; ++nt) {
            int n = colBase + nt * 16 + lrow;
#pragma unroll
            for (int r = 0; r < 4; ++r) {
                int m = rowBase + mt * 16 + quad * 4 + r;
                if (fin[nt][r] > SIM_THRESH) {
                    atomicAdd(&cb[m], 1);
                    if (!diag) atomicAdd(&cb[n], 1);
                }
            }
        }
    }
}

// ---------- L3: fix rows with cnt != 1 (cold; cnt==1 rows already hold out = v row) ----------
// V rows are recomputed on the fly here (k_main does not materialize v).
__global__ __launch_bounds__(256) void k_fix(
    const float* __restrict__ x,
    const float* __restrict__ Wq, const float* __restrict__ bq,
    const float* __restrict__ Wk, const float* __restrict__ bk,
    const float* __restrict__ Wv, const float* __restrict__ bv,
    const unsigned short* __restrict__ xn,
    const int* __restrict__ cnt,
    float* __restrict__ out)
{
    int tid = threadIdx.x;
    int rowBase = blockIdx.x * 256;

    __shared__ int list[256];
    __shared__ int nlist;
    if (tid == 0) nlist = 0;
    __syncthreads();
    int grow = rowBase + tid;
    if (cnt[grow] != 1) { int p = atomicAdd(&nlist, 1); list[p] = grow; }
    __syncthreads();
    int nfix = nlist;
    if (nfix == 0) return;

    __shared__ uint8_t mrow[SEQ];
    __shared__ float q_row[D_MODEL];
    __shared__ float k_row[D_MODEL];
    __shared__ float v_row[D_MODEL];
    __shared__ float accO[D_MODEL];
    __shared__ float m_h[NUM_HEADS], l_h[NUM_HEADS], alpha_h[NUM_HEADS], p_h[NUM_HEADS];

    for (int li = 0; li < nfix; ++li) {
        int row = list[li];
        int b = row >> 11, s = row & (SEQ - 1);

        const unsigned short* xs = xn + (size_t)row * D_MODEL;
        for (int t = tid; t < SEQ; t += 256) {
            const unsigned short* xt = xn + ((size_t)b * SEQ + t) * D_MODEL;
            float d = 0.f;
            for (int k = 0; k < D_MODEL; ++k) d += bf2f(xs[k]) * bf2f(xt[k]);
            mrow[t] = (d > SIM_THRESH) ? 1 : 0;
        }

        const float* xrow = x + (size_t)row * D_MODEL;
        for (int c = tid; c < D_MODEL; c += 256) {
            const float* w = Wq + (size_t)c * D_MODEL;
            float acc = bq[c];
            for (int d = 0; d < D_MODEL; ++d) acc += xrow[d] * w[d];
            q_row[c] = acc;
            accO[c] = 0.f;
        }
        if (tid < NUM_HEADS) { m_h[tid] = -INFINITY; l_h[tid] = 0.f; }
        __syncthreads();

        for (int t = 0; t < SEQ; ++t) {
            if (!mrow[t]) continue;
            const float* xt = x + ((size_t)b * SEQ + t) * D_MODEL;
            for (int c = tid; c < D_MODEL; c += 256) {
                const float* wk = Wk + (size_t)c * D_MODEL;
                const float* wv = Wv + (size_t)c * D_MODEL;
                float ak = bk[c], av = bv[c];
                for (int d = 0; d < D_MODEL; ++d) {
                    float xv = xt[d];
                    ak += xv * wk[d];
                    av += xv * wv[d];
                }
                k_row[c] = ak;
                v_row[c] = av;
            }
            __syncthreads();
            if (tid < NUM_HEADS) {
                float sc = 0.f;
                for (int j = 0; j < D_K; ++j) sc += q_row[tid * D_K + j] * k_row[tid * D_K + j];
                sc *= 0.125f;
                float mnew = fmaxf(m_h[tid], sc);
                float alpha = expf(m_h[tid] - mnew);
                float p = expf(sc - mnew);
                l_h[tid] = l_h[tid] * alpha + p;
                m_h[tid] = mnew;
                alpha_h[tid] = alpha;
                p_h[tid] = p;
            }
            __syncthreads();
            for (int c = tid; c < D_MODEL; c += 256) {
                int h = c >> 6;
                accO[c] = accO[c] * alpha_h[h] + p_h[h] * v_row[c];
            }
            __syncthreads();
        }
        for (int c = tid; c < D_MODEL; c += 256) {
            int h = c >> 6, j = c & 63;
            out[(((size_t)(b * NUM_HEADS + h)) * SEQ + s) * D_K + j] = accO[c] / l_h[h];
        }
        __syncthreads();
    }
}

extern "C" void kernel_launch(void* const* d_in, const int* in_sizes, int n_in,
                              void* d_out, int out_size, void* d_ws, size_t ws_size,
                              hipStream_t stream) {
    const float* x  = (const float*)d_in[0];
    const float* Wq = (const float*)d_in[1];
    const float* bq = (const float*)d_in[2];
    const float* Wk = (const float*)d_in[3];
    const float* bk = (const float*)d_in[4];
    const float* Wv = (const float*)d_in[5];
    const float* bv = (const float*)d_in[6];
    float* out = (float*)d_out;

    // workspace: xn bf16 (8MB) | Wvb bf16 (2MB) | norms (16KB) | cnt (16KB)
    unsigned short* xn  = (unsigned short*)d_ws;
    unsigned short* Wvb = xn + (size_t)NROWS * D_MODEL;
    float* norms = (float*)(Wvb + (size_t)D_MODEL * D_MODEL);
    int* cnt     = (int*)(norms + NROWS);

    // L1: 4096 row-normalize blocks + 1024 Wv-cast blocks
    k_prep<<<NROWS + D_MODEL * D_MODEL / 1024, 256, 0, stream>>>(x, Wv, xn, Wvb, norms, cnt);

    // L2: 1024 vproj tiles + 1056 sim tiles, 4 K-split waves each, barrier-free main loop
    k_main<<<GRID, 256, 0, stream>>>(xn, Wvb, bv, norms, cnt, out);

    // L3: fix non-singleton rows (cold)
    k_fix<<<NROWS / 256, 256, 0, stream>>>(x, Wq, bq, Wk, bk, Wv, bv, xn, cnt, out);
}

// Round 4
// 109.368 us; speedup vs baseline: 1.4490x; 1.4175x over previous
//
#include <hip/hip_runtime.h>
#include <stdint.h>
#include <math.h>

#define D_MODEL 1024
#define NUM_HEADS 16
#define D_K 64
#define SEQ 2048
#define BATCH 2
#define SIM_THRESH 0.7f
#define ITHRESH 11290        // 0.7 * 127^2 = 11290.3 ; integer dot > this => masked-in

#define TS 128               // tile size (square), m97 structure
#define BKV 32               // V-proj K chunk (bf16): 64B LDS rows
#define NITV (D_MODEL / BKV) // 32
#define BKS 64               // sim K chunk (i8): 64B LDS rows
#define NITS (D_MODEL / BKS) // 16

#define NROWS (BATCH * SEQ)                       // 4096
#define VP_BLOCKS ((NROWS / TS) * (D_MODEL / TS)) // 32*8 = 256
#define SIM_ROWB (SEQ / TS)                       // 16
#define SIM_TRI (SIM_ROWB * (SIM_ROWB + 1) / 2)   // 136
#define SIM_BLOCKS (SIM_TRI * BATCH)              // 272
#define GRID (VP_BLOCKS + SIM_BLOCKS)             // 528
#define VP_PER_XCD (VP_BLOCKS / 8)                // 32
#define SIM_PER_XCD (SIM_BLOCKS / 8)              // 34

#define TILE_B 8192          // one LDS tile buffer: 128 rows x 64 bytes

typedef __attribute__((ext_vector_type(8))) short bf16x8;
typedef __attribute__((ext_vector_type(4))) float f32x4;
typedef __attribute__((ext_vector_type(4))) int i32x4;

static __device__ __forceinline__ unsigned short f2bf(float f) {
    unsigned int u = __float_as_uint(f);
    unsigned int r = (u + 0x7FFF + ((u >> 16) & 1)) >> 16;   // RNE
    return (unsigned short)r;
}
static __device__ __forceinline__ float bf2f(unsigned short u) {
    return __uint_as_float(((unsigned int)u) << 16);
}

// ---------- L1: normalize x rows -> bf16 + i8 (+norms, zero cnt)  AND  cast Wv -> bf16 ----------
__global__ __launch_bounds__(256) void k_prep(const float* __restrict__ x,
                                              const float* __restrict__ Wv,
                                              unsigned short* __restrict__ xn,
                                              unsigned short* __restrict__ Wvb,
                                              char* __restrict__ xq,
                                              float* __restrict__ norms,
                                              int* __restrict__ cnt) {
    int bid = blockIdx.x, tid = threadIdx.x;
    if (bid < NROWS) {
        const float4* xr = (const float4*)(x + (size_t)bid * D_MODEL);
        float4 vv = xr[tid];
        float ss = vv.x * vv.x + vv.y * vv.y + vv.z * vv.z + vv.w * vv.w;
        for (int off = 32; off > 0; off >>= 1) ss += __shfl_down(ss, off, 64);
        __shared__ float wsum[4];
        int lane = tid & 63, wv = tid >> 6;
        if (lane == 0) wsum[wv] = ss;
        __syncthreads();
        float nrm = sqrtf(wsum[0] + wsum[1] + wsum[2] + wsum[3]);
        float inv = 1.0f / fmaxf(nrm, 1e-12f);
        float n0 = vv.x * inv, n1 = vv.y * inv, n2 = vv.z * inv, n3 = vv.w * inv;
        ushort4 o;
        o.x = f2bf(n0); o.y = f2bf(n1); o.z = f2bf(n2); o.w = f2bf(n3);
        *(ushort4*)(xn + (size_t)bid * D_MODEL + tid * 4) = o;
        char4 q;
        q.x = (char)__float2int_rn(n0 * 127.f);
        q.y = (char)__float2int_rn(n1 * 127.f);
        q.z = (char)__float2int_rn(n2 * 127.f);
        q.w = (char)__float2int_rn(n3 * 127.f);
        *(char4*)(xq + (size_t)bid * D_MODEL + tid * 4) = q;
        if (tid == 0) { norms[bid] = nrm; cnt[bid] = 0; }
    } else {
        size_t i = (size_t)(bid - NROWS) * 256 + tid;   // float4 chunk index
        float4 w = ((const float4*)Wv)[i];
        ushort4 o;
        o.x = f2bf(w.x); o.y = f2bf(w.y); o.z = f2bf(w.z); o.w = f2bf(w.w);
        *(ushort4*)(Wvb + i * 4) = o;
    }
}

// ---------- staging: 128 rows x 64 bytes, global -> LDS, 16B/lane async, 2 insts/thread ----------
static __device__ __forceinline__ void stage8k(const char* __restrict__ gsrc,
                                               int rowStrideB, int kByte,
                                               char* ldsDst, int tid) {
#pragma unroll
    for (int i = 0; i < 2; ++i) {
        int c   = i * 256 + tid;        // 16B chunk id, 0..511
        int row = c >> 2;               // 0..127
        int ch  = c & 3;                // 4 x 16B chunks per 64B row
        const char* ga = gsrc + (size_t)row * rowStrideB + kByte + ch * 16;
        __builtin_amdgcn_global_load_lds(
            (const __attribute__((address_space(1))) unsigned int*)ga,
            (__attribute__((address_space(3))) unsigned int*)(ldsDst + c * 16),
            16, 0, 0);
    }
}

// ---------- L2: fused V-proj (bf16 MFMA) + symmetric sim/count (i8 MFMA, 2x K rate) ----------
// 128x128 tiles, double-buffered 64B-row LDS (32 KB). 4 waves as 2x2, 64x64 per wave,
// 4x4 fragments. launch_bounds(256,3) caps regs at 170 -> 3 blocks/CU resident.
// Block map: XCD x gets 32 vproj blocks (first) + 34 sim blocks (tail filler).
__global__ __launch_bounds__(256, 3) void k_main(const unsigned short* __restrict__ xn,
                                                 const unsigned short* __restrict__ Wvb,
                                                 const char* __restrict__ xq,
                                                 const float* __restrict__ bv,
                                                 const float* __restrict__ norms,
                                                 int* __restrict__ cnt,
                                                 float* __restrict__ out) {
    __shared__ char As[2 * TILE_B];
    __shared__ char Bs[2 * TILE_B];
    int bid0 = blockIdx.x;
    int xcd = bid0 & 7, l = bid0 >> 3;     // bid0&7 tracks XCD assignment on gfx950
    int tid = threadIdx.x;
    int lane = tid & 63, wave = tid >> 6;
    int wm = wave & 1, wn = wave >> 1;
    int lrow = lane & 15, quad = lane >> 4;

    bool isV = (l < VP_PER_XCD);

    // per-lane fragment byte offsets inside a [128][64B] LDS tile (identical both paths)
    int aoffB[4], boffB[4];
#pragma unroll
    for (int i = 0; i < 4; ++i) {
        aoffB[i] = (wm * 64 + i * 16 + lrow) * 64 + quad * 16;
        boffB[i] = (wn * 64 + i * 16 + lrow) * 64 + quad * 16;
    }

    if (isV) {
        int bid = xcd * VP_PER_XCD + l;        // 0..255
        int rowBase = (bid >> 3) * TS;         // 32 row-blocks
        int colBase = (bid & 7) * TS;          // 8 col-blocks
        const char* Asrc = (const char*)(xn + (size_t)rowBase * D_MODEL);
        const char* Bsrc = (const char*)(Wvb + (size_t)colBase * D_MODEL);

        f32x4 acc[4][4] = {};
        stage8k(Asrc, D_MODEL * 2, 0, As, tid);
        stage8k(Bsrc, D_MODEL * 2, 0, Bs, tid);
        __syncthreads();
        for (int it = 0; it < NITV; ++it) {
            int cur = it & 1, nxt = cur ^ 1;
            if (it + 1 < NITV) {
                stage8k(Asrc, D_MODEL * 2, (it + 1) * 64, As + nxt * TILE_B, tid);
                stage8k(Bsrc, D_MODEL * 2, (it + 1) * 64, Bs + nxt * TILE_B, tid);
            }
            const char* Ac = As + cur * TILE_B;
            const char* Bc = Bs + cur * TILE_B;
            bf16x8 av[4], bw[4];
#pragma unroll
            for (int i = 0; i < 4; ++i) av[i] = *(const bf16x8*)(Ac + aoffB[i]);
#pragma unroll
            for (int i = 0; i < 4; ++i) bw[i] = *(const bf16x8*)(Bc + boffB[i]);
#pragma unroll
            for (int mt = 0; mt < 4; ++mt)
#pragma unroll
                for (int nt = 0; nt < 4; ++nt)
                    acc[mt][nt] = __builtin_amdgcn_mfma_f32_16x16x32_bf16(av[mt], bw[nt], acc[mt][nt], 0, 0, 0);
            __syncthreads();
        }
#pragma unroll
        for (int nt = 0; nt < 4; ++nt) {
            int n = colBase + wn * 64 + nt * 16 + lrow;
            float bn = bv[n];
            int h = n >> 6, j = n & 63;
#pragma unroll
            for (int mt = 0; mt < 4; ++mt) {
#pragma unroll
                for (int r = 0; r < 4; ++r) {
                    int m = rowBase + wm * 64 + mt * 16 + quad * 4 + r;
                    float val = acc[mt][nt][r] * norms[m] + bn;
                    int bb = m >> 11, s = m & (SEQ - 1);
                    out[(((size_t)(bb * NUM_HEADS + h)) * SEQ + s) * D_K + j] = val;
                }
            }
        }
    } else {
        int sidx = xcd * SIM_PER_XCD + (l - VP_PER_XCD);   // 0..271
        int b = (sidx >= SIM_TRI) ? 1 : 0;
        int r0 = sidx - b * SIM_TRI;
        int bi = 0;
        while (r0 >= SIM_ROWB - bi) { r0 -= SIM_ROWB - bi; ++bi; }
        int bj = bi + r0;
        int rowBase = bi * TS;              // batch-local
        int colBase = bj * TS;
        const char* base = xq + (size_t)b * SEQ * D_MODEL;
        const char* Asrc = base + (size_t)rowBase * D_MODEL;
        const char* Bsrc = base + (size_t)colBase * D_MODEL;

        i32x4 acc[4][4] = {};
        stage8k(Asrc, D_MODEL, 0, As, tid);
        stage8k(Bsrc, D_MODEL, 0, Bs, tid);
        __syncthreads();
        for (int it = 0; it < NITS; ++it) {
            int cur = it & 1, nxt = cur ^ 1;
            if (it + 1 < NITS) {
                stage8k(Asrc, D_MODEL, (it + 1) * 64, As + nxt * TILE_B, tid);
                stage8k(Bsrc, D_MODEL, (it + 1) * 64, Bs + nxt * TILE_B, tid);
            }
            const char* Ac = As + cur * TILE_B;
            const char* Bc = Bs + cur * TILE_B;
            i32x4 av[4], bw[4];
#pragma unroll
            for (int i = 0; i < 4; ++i) av[i] = *(const i32x4*)(Ac + aoffB[i]);
#pragma unroll
            for (int i = 0; i < 4; ++i) bw[i] = *(const i32x4*)(Bc + boffB[i]);
#pragma unroll
            for (int mt = 0; mt < 4; ++mt)
#pragma unroll
                for (int nt = 0; nt < 4; ++nt)
                    acc[mt][nt] = __builtin_amdgcn_mfma_i32_16x16x64_i8(av[mt], bw[nt], acc[mt][nt], 0, 0, 0);
            __syncthreads();
        }
        int* cb = cnt + b * SEQ;
        bool diag = (bi == bj);
#pragma unroll
        for (int nt = 0; nt < 4; ++nt) {
            int n = colBase + wn * 64 + nt * 16 + lrow;
#pragma unroll
            for (int mt = 0; mt < 4; ++mt) {
#pragma unroll
                for (int r = 0; r < 4; ++r) {
                    int m = rowBase + wm * 64 + mt * 16 + quad * 4 + r;
                    if (acc[mt][nt][r] > ITHRESH) {
                        atomicAdd(&cb[m], 1);
                        if (!diag) atomicAdd(&cb[n], 1);
                    }
                }
            }
        }
    }
}

// ---------- L3: fix rows with cnt != 1 (cold; cnt==1 rows already hold out = v row) ----------
__global__ __launch_bounds__(256) void k_fix(
    const float* __restrict__ x,
    const float* __restrict__ Wq, const float* __restrict__ bq,
    const float* __restrict__ Wk, const float* __restrict__ bk,
    const float* __restrict__ Wv, const float* __restrict__ bv,
    const unsigned short* __restrict__ xn,
    const int* __restrict__ cnt,
    float* __restrict__ out)
{
    int tid = threadIdx.x;
    int rowBase = blockIdx.x * 256;

    __shared__ int list[256];
    __shared__ int nlist;
    if (tid == 0) nlist = 0;
    __syncthreads();
    int grow = rowBase + tid;
    if (cnt[grow] != 1) { int p = atomicAdd(&nlist, 1); list[p] = grow; }
    __syncthreads();
    int nfix = nlist;
    if (nfix == 0) return;

    __shared__ uint8_t mrow[SEQ];
    __shared__ float q_row[D_MODEL];
    __shared__ float k_row[D_MODEL];
    __shared__ float v_row[D_MODEL];
    __shared__ float accO[D_MODEL];
    __shared__ float m_h[NUM_HEADS], l_h[NUM_HEADS], alpha_h[NUM_HEADS], p_h[NUM_HEADS];

    for (int li = 0; li < nfix; ++li) {
        int row = list[li];
        int b = row >> 11, s = row & (SEQ - 1);

        const unsigned short* xs = xn + (size_t)row * D_MODEL;
        for (int t = tid; t < SEQ; t += 256) {
            const unsigned short* xt = xn + ((size_t)b * SEQ + t) * D_MODEL;
            float d = 0.f;
            for (int k = 0; k < D_MODEL; ++k) d += bf2f(xs[k]) * bf2f(xt[k]);
            mrow[t] = (d > SIM_THRESH) ? 1 : 0;
        }

        const float* xrow = x + (size_t)row * D_MODEL;
        for (int c = tid; c < D_MODEL; c += 256) {
            const float* w = Wq + (size_t)c * D_MODEL;
            float acc = bq[c];
            for (int d = 0; d < D_MODEL; ++d) acc += xrow[d] * w[d];
            q_row[c] = acc;
            accO[c] = 0.f;
        }
        if (tid < NUM_HEADS) { m_h[tid] = -INFINITY; l_h[tid] = 0.f; }
        __syncthreads();

        for (int t = 0; t < SEQ; ++t) {
            if (!mrow[t]) continue;
            const float* xt = x + ((size_t)b * SEQ + t) * D_MODEL;
            for (int c = tid; c < D_MODEL; c += 256) {
                const float* wk = Wk + (size_t)c * D_MODEL;
                const float* wv = Wv + (size_t)c * D_MODEL;
                float ak = bk[c], av = bv[c];
                for (int d = 0; d < D_MODEL; ++d) {
                    float xv = xt[d];
                    ak += xv * wk[d];
                    av += xv * wv[d];
                }
                k_row[c] = ak;
                v_row[c] = av;
            }
            __syncthreads();
            if (tid < NUM_HEADS) {
                float sc = 0.f;
                for (int j = 0; j < D_K; ++j) sc += q_row[tid * D_K + j] * k_row[tid * D_K + j];
                sc *= 0.125f;
                float mnew = fmaxf(m_h[tid], sc);
                float alpha = expf(m_h[tid] - mnew);
                float p = expf(sc - mnew);
                l_h[tid] = l_h[tid] * alpha + p;
                m_h[tid] = mnew;
                alpha_h[tid] = alpha;
                p_h[tid] = p;
            }
            __syncthreads();
            for (int c = tid; c < D_MODEL; c += 256) {
                int h = c >> 6;
                accO[c] = accO[c] * alpha_h[h] + p_h[h] * v_row[c];
            }
            __syncthreads();
        }
        for (int c = tid; c < D_MODEL; c += 256) {
            int h = c >> 6, j = c & 63;
            out[(((size_t)(b * NUM_HEADS + h)) * SEQ + s) * D_K + j] = accO[c] / l_h[h];
        }
        __syncthreads();
    }
}

extern "C" void kernel_launch(void* const* d_in, const int* in_sizes, int n_in,
                              void* d_out, int out_size, void* d_ws, size_t ws_size,
                              hipStream_t stream) {
    const float* x  = (const float*)d_in[0];
    const float* Wq = (const float*)d_in[1];
    const float* bq = (const float*)d_in[2];
    const float* Wk = (const float*)d_in[3];
    const float* bk = (const float*)d_in[4];
    const float* Wv = (const float*)d_in[5];
    const float* bv = (const float*)d_in[6];
    float* out = (float*)d_out;

    // workspace: xn bf16 (8MB) | Wvb bf16 (2MB) | xq i8 (4MB) | norms (16KB) | cnt (16KB)
    unsigned short* xn  = (unsigned short*)d_ws;
    unsigned short* Wvb = xn + (size_t)NROWS * D_MODEL;
    char* xq     = (char*)(Wvb + (size_t)D_MODEL * D_MODEL);
    float* norms = (float*)(xq + (size_t)NROWS * D_MODEL);
    int* cnt     = (int*)(norms + NROWS);

    // L1: 4096 row-normalize blocks + 1024 Wv-cast blocks
    k_prep<<<NROWS + D_MODEL * D_MODEL / 1024, 256, 0, stream>>>(x, Wv, xn, Wvb, xq, norms, cnt);

    // L2: 256 vproj tiles (bf16) + 272 sim tiles (i8), XCD-balanced
    k_main<<<GRID, 256, 0, stream>>>(xn, Wvb, xq, bv, norms, cnt, out);

    // L3: fix non-singleton rows (cold)
    k_fix<<<NROWS / 256, 256, 0, stream>>>(x, Wq, bq, Wk, bk, Wv, bv, xn, cnt, out);
}